// Round 1
// baseline (1948.939 us; speedup 1.0000x reference)
//
#include <hip/hip_runtime.h>
#include <hip/hip_bf16.h>

// ---------------------------------------------------------------------------
// Pipeline (W1 pushed through the linear aggregation):
//   xg1  = x_goal @ W1                      [16384,64]
//   acc1 = x_obs  @ W1                      [65536,64]
//   acc1 += scatter(xg1[go_src] -> go_dst)  (atomics)
//   x1   = relu(relu(acc1 + b1) @ W2 + b2)  [65536,64]
//   acc2 = 0; acc2 += scatter(x1[ot_src] -> ot_dst)   [8192,64]
//   g    = relu((x_task + acc2) @ W3 + b3); x2 = g @ W4 + b4   [8192]
//   per-graph (32 nodes) max/mean pool -> critic MLP -> out[256]
// ---------------------------------------------------------------------------

// out[M,64] = X[M,128] @ W[128,64]   (no bias)
__global__ __launch_bounds__(256) void gemm_k128(
    const float* __restrict__ X, const float* __restrict__ W,
    float* __restrict__ out, int M)
{
    __shared__ float Ws[128 * 64];
    __shared__ float Xs[16 * 132];       // stride 132: 4-bank skew per row
    const int tid = threadIdx.x;
    for (int i = tid; i < 128 * 64 / 4; i += 256)
        ((float4*)Ws)[i] = ((const float4*)W)[i];
    const int row0 = blockIdx.x * 16;
    for (int i = tid; i < 16 * 32; i += 256) {
        int r = i >> 5, c4 = i & 31;
        float4 v = ((const float4*)(X + (size_t)(row0 + r) * 128))[c4];
        *((float4*)(Xs + r * 132 + c4 * 4)) = v;
    }
    __syncthreads();
    const int rl = tid >> 4;             // 0..15 row in chunk
    const int cg = (tid & 15) * 4;       // column group
    float a0 = 0.f, a1 = 0.f, a2 = 0.f, a3 = 0.f;
    const float* xr = Xs + rl * 132;
    #pragma unroll 8
    for (int k = 0; k < 128; ++k) {
        float xv = xr[k];
        float4 wv = *((const float4*)(Ws + k * 64 + cg));
        a0 = fmaf(xv, wv.x, a0);
        a1 = fmaf(xv, wv.y, a1);
        a2 = fmaf(xv, wv.z, a2);
        a3 = fmaf(xv, wv.w, a3);
    }
    float4 o; o.x = a0; o.y = a1; o.z = a2; o.w = a3;
    *((float4*)(out + (size_t)(row0 + rl) * 64 + cg)) = o;
}

// acc[dst[e]] += table[src[e]]  (64-wide rows, 16 threads/edge, float4 each)
__global__ __launch_bounds__(256) void scatter_add64(
    const int* __restrict__ src, const int* __restrict__ dst,
    const float* __restrict__ table, float* __restrict__ acc, int E)
{
    int t = blockIdx.x * 256 + threadIdx.x;
    int e = t >> 4;
    if (e >= E) return;
    int c = (t & 15) * 4;
    int s = src[e];
    int d = dst[e];
    float4 v = *((const float4*)(table + (size_t)s * 64 + c));
    float* a = acc + (size_t)d * 64 + c;
    unsafeAtomicAdd(a + 0, v.x);
    unsafeAtomicAdd(a + 1, v.y);
    unsafeAtomicAdd(a + 2, v.z);
    unsafeAtomicAdd(a + 3, v.w);
}

// out = relu(relu(in + b1) @ W2 + b2)   (64 -> 64)
__global__ __launch_bounds__(256) void mlp_obs(
    const float* __restrict__ in, const float* __restrict__ b1,
    const float* __restrict__ W2, const float* __restrict__ b2,
    float* __restrict__ out, int M)
{
    __shared__ float Ws[64 * 64];
    __shared__ float Hs[16 * 68];
    const int tid = threadIdx.x;
    for (int i = tid; i < 64 * 64 / 4; i += 256)
        ((float4*)Ws)[i] = ((const float4*)W2)[i];
    const int row0 = blockIdx.x * 16;
    {
        int r = tid >> 4, c4 = tid & 15;
        float4 v = ((const float4*)(in + (size_t)(row0 + r) * 64))[c4];
        float4 bb = ((const float4*)b1)[c4];
        v.x = fmaxf(v.x + bb.x, 0.f);
        v.y = fmaxf(v.y + bb.y, 0.f);
        v.z = fmaxf(v.z + bb.z, 0.f);
        v.w = fmaxf(v.w + bb.w, 0.f);
        *((float4*)(Hs + r * 68 + c4 * 4)) = v;
    }
    __syncthreads();
    const int rl = tid >> 4, cg = (tid & 15) * 4;
    float4 bb2 = *((const float4*)(b2 + cg));
    float a0 = bb2.x, a1 = bb2.y, a2 = bb2.z, a3 = bb2.w;
    const float* hr = Hs + rl * 68;
    #pragma unroll 8
    for (int k = 0; k < 64; ++k) {
        float xv = hr[k];
        float4 wv = *((const float4*)(Ws + k * 64 + cg));
        a0 = fmaf(xv, wv.x, a0);
        a1 = fmaf(xv, wv.y, a1);
        a2 = fmaf(xv, wv.z, a2);
        a3 = fmaf(xv, wv.w, a3);
    }
    float4 o;
    o.x = fmaxf(a0, 0.f); o.y = fmaxf(a1, 0.f);
    o.z = fmaxf(a2, 0.f); o.w = fmaxf(a3, 0.f);
    *((float4*)(out + (size_t)(row0 + rl) * 64 + cg)) = o;
}

// g = relu((x_task + acc2) @ W3 + b3); x2 = g @ W4 + b4
__global__ __launch_bounds__(256) void mlp_task(
    const float* __restrict__ x_task, const float* __restrict__ acc2,
    const float* __restrict__ W3, const float* __restrict__ b3,
    const float* __restrict__ W4, const float* __restrict__ b4,
    float* __restrict__ x2, int M)
{
    __shared__ float Ws[64 * 64];
    __shared__ float Ts[16 * 68];
    const int tid = threadIdx.x;
    for (int i = tid; i < 64 * 64 / 4; i += 256)
        ((float4*)Ws)[i] = ((const float4*)W3)[i];
    const int row0 = blockIdx.x * 16;
    {
        int r = tid >> 4, c4 = tid & 15;
        size_t off = (size_t)(row0 + r) * 64;
        float4 v = ((const float4*)(x_task + off))[c4];
        float4 u = ((const float4*)(acc2 + off))[c4];
        v.x += u.x; v.y += u.y; v.z += u.z; v.w += u.w;
        *((float4*)(Ts + r * 68 + c4 * 4)) = v;
    }
    __syncthreads();
    const int rl = tid >> 4, cg = (tid & 15) * 4;
    float4 bb = *((const float4*)(b3 + cg));
    float a0 = bb.x, a1 = bb.y, a2 = bb.z, a3 = bb.w;
    const float* tr = Ts + rl * 68;
    #pragma unroll 8
    for (int k = 0; k < 64; ++k) {
        float xv = tr[k];
        float4 wv = *((const float4*)(Ws + k * 64 + cg));
        a0 = fmaf(xv, wv.x, a0);
        a1 = fmaf(xv, wv.y, a1);
        a2 = fmaf(xv, wv.z, a2);
        a3 = fmaf(xv, wv.w, a3);
    }
    float4 w4 = *((const float4*)(W4 + cg));
    float p = fmaxf(a0, 0.f) * w4.x + fmaxf(a1, 0.f) * w4.y
            + fmaxf(a2, 0.f) * w4.z + fmaxf(a3, 0.f) * w4.w;
    // reduce across the 16 lanes handling this row (contiguous lanes in-wave)
    p += __shfl_xor(p, 1);
    p += __shfl_xor(p, 2);
    p += __shfl_xor(p, 4);
    p += __shfl_xor(p, 8);
    if ((tid & 15) == 0)
        x2[row0 + rl] = p + b4[0];
}

// per-graph (32 contiguous task nodes) max/mean pool + critic MLP
__global__ __launch_bounds__(256) void pool_critic(
    const float* __restrict__ x2, const float* __restrict__ Wc1,
    const float* __restrict__ bc1, const float* __restrict__ Wc2,
    const float* __restrict__ bc2, float* __restrict__ out)
{
    int b = threadIdx.x;                 // 256 graphs, one thread each
    const float* p = x2 + b * 32;
    float mx = -1e30f, sm = 0.f;
    #pragma unroll
    for (int i = 0; i < 32; ++i) { float v = p[i]; mx = fmaxf(mx, v); sm += v; }
    float mn = sm * (1.f / 32.f);
    float o = bc2[0];
    #pragma unroll
    for (int j = 0; j < 8; ++j) {
        float t = fmaxf(mx * Wc1[j] + mn * Wc1[8 + j] + bc1[j], 0.f);
        o = fmaf(t, Wc2[j], o);
    }
    out[b] = o;
}

extern "C" void kernel_launch(void* const* d_in, const int* in_sizes, int n_in,
                              void* d_out, int out_size, void* d_ws, size_t ws_size,
                              hipStream_t stream)
{
    const float* x_goal = (const float*)d_in[0];
    const float* x_obs  = (const float*)d_in[1];
    const float* x_task = (const float*)d_in[2];
    const int* go_src = (const int*)d_in[3];
    const int* go_dst = (const int*)d_in[4];
    const int* ot_src = (const int*)d_in[5];
    const int* ot_dst = (const int*)d_in[6];
    // d_in[7] task_batch: contiguous 32 nodes/graph -- index arithmetic instead
    const float* W1  = (const float*)d_in[8];
    const float* b1  = (const float*)d_in[9];
    const float* W2  = (const float*)d_in[10];
    const float* b2  = (const float*)d_in[11];
    const float* W3  = (const float*)d_in[12];
    const float* b3  = (const float*)d_in[13];
    const float* W4  = (const float*)d_in[14];
    const float* b4  = (const float*)d_in[15];
    const float* Wc1 = (const float*)d_in[16];
    const float* bc1 = (const float*)d_in[17];
    const float* Wc2 = (const float*)d_in[18];
    const float* bc2 = (const float*)d_in[19];
    float* out = (float*)d_out;

    const int N_GOAL = 16384, N_OBS = 65536, N_TASK = 8192;
    const int E1 = in_sizes[3], E2 = in_sizes[5];

    float* ws   = (float*)d_ws;
    float* xg1  = ws;                                  //  4 MB
    float* acc1 = xg1 + (size_t)N_GOAL * 64;           // 16 MB
    float* x1   = acc1 + (size_t)N_OBS * 64;           // 16 MB
    float* acc2 = x1 + (size_t)N_OBS * 64;             //  2 MB
    float* x2   = acc2 + (size_t)N_TASK * 64;          // 32 KB

    hipMemsetAsync(acc2, 0, (size_t)N_TASK * 64 * sizeof(float), stream);
    gemm_k128<<<N_GOAL / 16, 256, 0, stream>>>(x_goal, W1, xg1, N_GOAL);
    gemm_k128<<<N_OBS / 16, 256, 0, stream>>>(x_obs, W1, acc1, N_OBS);
    scatter_add64<<<(E1 * 16 + 255) / 256, 256, 0, stream>>>(go_src, go_dst, xg1, acc1, E1);
    mlp_obs<<<N_OBS / 16, 256, 0, stream>>>(acc1, b1, W2, b2, x1, N_OBS);
    scatter_add64<<<(E2 * 16 + 255) / 256, 256, 0, stream>>>(ot_src, ot_dst, x1, acc2, E2);
    mlp_task<<<N_TASK / 16, 256, 0, stream>>>(x_task, acc2, W3, b3, W4, b4, x2, N_TASK);
    pool_critic<<<1, 256, 0, stream>>>(x2, Wc1, bc1, Wc2, bc2, out);
}

// Round 2
// 487.207 us; speedup vs baseline: 4.0002x; 4.0002x over previous
//
#include <hip/hip_runtime.h>
#include <hip/hip_bf16.h>

// ---------------------------------------------------------------------------
// Pipeline (W1 pushed through the linear aggregation; scatters inverted to
// CSR gathers to eliminate float atomics — round-1 counters showed 91% of
// time in global_atomic_add_f32 with 1 GB write-through per scatter):
//   CSR1 = bucket(go_dst)                          [per call, int atomics]
//   xg1  = x_goal @ W1                             [16384,64]
//   obs  = x_obs  @ W1                             [65536,64]
//   obs[d] += sum_{e in CSR1[d]} xg1[src[e]]       (gather, no atomics)
//   obs  = relu(relu(obs + b1) @ W2 + b2)          (in-place)
//   CSR2 = bucket(ot_dst)
//   acc2[d] = sum_{e in CSR2[d]} obs[src[e]]       [8192,64]
//   g    = relu((x_task + acc2) @ W3 + b3); x2 = g @ W4 + b4   [8192]
//   per-graph (32 nodes) max/mean pool -> critic MLP -> out[256]
// ---------------------------------------------------------------------------

// out[M,64] = X[M,128] @ W[128,64]   (no bias)
__global__ __launch_bounds__(256) void gemm_k128(
    const float* __restrict__ X, const float* __restrict__ W,
    float* __restrict__ out, int M)
{
    __shared__ float Ws[128 * 64];
    __shared__ float Xs[16 * 132];       // stride 132: 4-bank skew per row
    const int tid = threadIdx.x;
    for (int i = tid; i < 128 * 64 / 4; i += 256)
        ((float4*)Ws)[i] = ((const float4*)W)[i];
    const int row0 = blockIdx.x * 16;
    for (int i = tid; i < 16 * 32; i += 256) {
        int r = i >> 5, c4 = i & 31;
        float4 v = ((const float4*)(X + (size_t)(row0 + r) * 128))[c4];
        *((float4*)(Xs + r * 132 + c4 * 4)) = v;
    }
    __syncthreads();
    const int rl = tid >> 4;             // 0..15 row in chunk
    const int cg = (tid & 15) * 4;       // column group
    float a0 = 0.f, a1 = 0.f, a2 = 0.f, a3 = 0.f;
    const float* xr = Xs + rl * 132;
    #pragma unroll 8
    for (int k = 0; k < 128; ++k) {
        float xv = xr[k];
        float4 wv = *((const float4*)(Ws + k * 64 + cg));
        a0 = fmaf(xv, wv.x, a0);
        a1 = fmaf(xv, wv.y, a1);
        a2 = fmaf(xv, wv.z, a2);
        a3 = fmaf(xv, wv.w, a3);
    }
    float4 o; o.x = a0; o.y = a1; o.z = a2; o.w = a3;
    *((float4*)(out + (size_t)(row0 + rl) * 64 + cg)) = o;
}

// --------------------------- CSR construction -----------------------------

__global__ __launch_bounds__(256) void hist_kernel(
    const int* __restrict__ dst, int* __restrict__ cnt, int E)
{
    int i = blockIdx.x * 256 + threadIdx.x;
    if (i < E) atomicAdd(&cnt[dst[i]], 1);
}

// counts (in cnt) -> exclusive prefix in-place (becomes fill cursor) and in
// offs; offs[M] = total. Single workgroup of 1024 threads, PER elems each.
template <int M, int PER>
__global__ __launch_bounds__(1024) void scan_csr(
    int* __restrict__ cnt, int* __restrict__ offs)
{
    __shared__ int part[1024];
    const int t = threadIdx.x;
    const int base = t * PER;
    int vals[PER];
    int s = 0;
    #pragma unroll
    for (int i = 0; i < PER; ++i) { vals[i] = cnt[base + i]; s += vals[i]; }
    part[t] = s;
    __syncthreads();
    for (int off = 1; off < 1024; off <<= 1) {
        int v = (t >= off) ? part[t - off] : 0;
        __syncthreads();
        part[t] += v;
        __syncthreads();
    }
    int run = (t == 0) ? 0 : part[t - 1];
    #pragma unroll
    for (int i = 0; i < PER; ++i) {
        int c = vals[i];
        cnt[base + i] = run;
        offs[base + i] = run;
        run += c;
    }
    if (t == 1023) offs[M] = run;      // == E
}

__global__ __launch_bounds__(256) void fill_kernel(
    const int* __restrict__ src, const int* __restrict__ dst,
    int* __restrict__ cur, int* __restrict__ sorted, int E)
{
    int i = blockIdx.x * 256 + threadIdx.x;
    if (i < E) {
        int p = atomicAdd(&cur[dst[i]], 1);
        sorted[p] = src[i];
    }
}

// ------------------------------- gather -----------------------------------
// One wave per dst row. 4 lane-groups x 16 lanes; each lane owns a float4
// column slice; groups stride the edge list; shfl-reduce; one store per row.
template <bool ADD_BASE>
__global__ __launch_bounds__(256) void gather_add64(
    const int* __restrict__ offs, const int* __restrict__ srcs,
    const float* __restrict__ table, float* __restrict__ acc, int M)
{
    const int row = blockIdx.x * 4 + (threadIdx.x >> 6);
    const int lane = threadIdx.x & 63;
    const int grp = lane >> 4;
    const int c = (lane & 15) * 4;
    const int beg = offs[row], end = offs[row + 1];
    float4 s; s.x = 0.f; s.y = 0.f; s.z = 0.f; s.w = 0.f;
    for (int e = beg + grp; e < end; e += 4) {
        int si = srcs[e];                               // broadcast within group
        float4 v = *((const float4*)(table + (size_t)si * 64 + c));
        s.x += v.x; s.y += v.y; s.z += v.z; s.w += v.w;
    }
    s.x += __shfl_xor(s.x, 16); s.y += __shfl_xor(s.y, 16);
    s.z += __shfl_xor(s.z, 16); s.w += __shfl_xor(s.w, 16);
    s.x += __shfl_xor(s.x, 32); s.y += __shfl_xor(s.y, 32);
    s.z += __shfl_xor(s.z, 32); s.w += __shfl_xor(s.w, 32);
    if (grp == 0) {
        float* p = acc + (size_t)row * 64 + c;
        if (ADD_BASE) {
            float4 b = *((const float4*)p);
            s.x += b.x; s.y += b.y; s.z += b.z; s.w += b.w;
        }
        *((float4*)p) = s;
    }
}

// out = relu(relu(in + b1) @ W2 + b2)   (64 -> 64); safe when out == in
__global__ __launch_bounds__(256) void mlp_obs(
    const float* __restrict__ in, const float* __restrict__ b1,
    const float* __restrict__ W2, const float* __restrict__ b2,
    float* __restrict__ out, int M)
{
    __shared__ float Ws[64 * 64];
    __shared__ float Hs[16 * 68];
    const int tid = threadIdx.x;
    for (int i = tid; i < 64 * 64 / 4; i += 256)
        ((float4*)Ws)[i] = ((const float4*)W2)[i];
    const int row0 = blockIdx.x * 16;
    {
        int r = tid >> 4, c4 = tid & 15;
        float4 v = ((const float4*)(in + (size_t)(row0 + r) * 64))[c4];
        float4 bb = ((const float4*)b1)[c4];
        v.x = fmaxf(v.x + bb.x, 0.f);
        v.y = fmaxf(v.y + bb.y, 0.f);
        v.z = fmaxf(v.z + bb.z, 0.f);
        v.w = fmaxf(v.w + bb.w, 0.f);
        *((float4*)(Hs + r * 68 + c4 * 4)) = v;
    }
    __syncthreads();
    const int rl = tid >> 4, cg = (tid & 15) * 4;
    float4 bb2 = *((const float4*)(b2 + cg));
    float a0 = bb2.x, a1 = bb2.y, a2 = bb2.z, a3 = bb2.w;
    const float* hr = Hs + rl * 68;
    #pragma unroll 8
    for (int k = 0; k < 64; ++k) {
        float xv = hr[k];
        float4 wv = *((const float4*)(Ws + k * 64 + cg));
        a0 = fmaf(xv, wv.x, a0);
        a1 = fmaf(xv, wv.y, a1);
        a2 = fmaf(xv, wv.z, a2);
        a3 = fmaf(xv, wv.w, a3);
    }
    float4 o;
    o.x = fmaxf(a0, 0.f); o.y = fmaxf(a1, 0.f);
    o.z = fmaxf(a2, 0.f); o.w = fmaxf(a3, 0.f);
    *((float4*)(out + (size_t)(row0 + rl) * 64 + cg)) = o;
}

// g = relu((x_task + acc2) @ W3 + b3); x2 = g @ W4 + b4
__global__ __launch_bounds__(256) void mlp_task(
    const float* __restrict__ x_task, const float* __restrict__ acc2,
    const float* __restrict__ W3, const float* __restrict__ b3,
    const float* __restrict__ W4, const float* __restrict__ b4,
    float* __restrict__ x2, int M)
{
    __shared__ float Ws[64 * 64];
    __shared__ float Ts[16 * 68];
    const int tid = threadIdx.x;
    for (int i = tid; i < 64 * 64 / 4; i += 256)
        ((float4*)Ws)[i] = ((const float4*)W3)[i];
    const int row0 = blockIdx.x * 16;
    {
        int r = tid >> 4, c4 = tid & 15;
        size_t off = (size_t)(row0 + r) * 64;
        float4 v = ((const float4*)(x_task + off))[c4];
        float4 u = ((const float4*)(acc2 + off))[c4];
        v.x += u.x; v.y += u.y; v.z += u.z; v.w += u.w;
        *((float4*)(Ts + r * 68 + c4 * 4)) = v;
    }
    __syncthreads();
    const int rl = tid >> 4, cg = (tid & 15) * 4;
    float4 bb = *((const float4*)(b3 + cg));
    float a0 = bb.x, a1 = bb.y, a2 = bb.z, a3 = bb.w;
    const float* tr = Ts + rl * 68;
    #pragma unroll 8
    for (int k = 0; k < 64; ++k) {
        float xv = tr[k];
        float4 wv = *((const float4*)(Ws + k * 64 + cg));
        a0 = fmaf(xv, wv.x, a0);
        a1 = fmaf(xv, wv.y, a1);
        a2 = fmaf(xv, wv.z, a2);
        a3 = fmaf(xv, wv.w, a3);
    }
    float4 w4 = *((const float4*)(W4 + cg));
    float p = fmaxf(a0, 0.f) * w4.x + fmaxf(a1, 0.f) * w4.y
            + fmaxf(a2, 0.f) * w4.z + fmaxf(a3, 0.f) * w4.w;
    p += __shfl_xor(p, 1);
    p += __shfl_xor(p, 2);
    p += __shfl_xor(p, 4);
    p += __shfl_xor(p, 8);
    if ((tid & 15) == 0)
        x2[row0 + rl] = p + b4[0];
}

// per-graph (32 contiguous task nodes) max/mean pool + critic MLP
__global__ __launch_bounds__(256) void pool_critic(
    const float* __restrict__ x2, const float* __restrict__ Wc1,
    const float* __restrict__ bc1, const float* __restrict__ Wc2,
    const float* __restrict__ bc2, float* __restrict__ out)
{
    int b = threadIdx.x;
    const float* p = x2 + b * 32;
    float mx = -1e30f, sm = 0.f;
    #pragma unroll
    for (int i = 0; i < 32; ++i) { float v = p[i]; mx = fmaxf(mx, v); sm += v; }
    float mn = sm * (1.f / 32.f);
    float o = bc2[0];
    #pragma unroll
    for (int j = 0; j < 8; ++j) {
        float t = fmaxf(mx * Wc1[j] + mn * Wc1[8 + j] + bc1[j], 0.f);
        o = fmaf(t, Wc2[j], o);
    }
    out[b] = o;
}

extern "C" void kernel_launch(void* const* d_in, const int* in_sizes, int n_in,
                              void* d_out, int out_size, void* d_ws, size_t ws_size,
                              hipStream_t stream)
{
    const float* x_goal = (const float*)d_in[0];
    const float* x_obs  = (const float*)d_in[1];
    const float* x_task = (const float*)d_in[2];
    const int* go_src = (const int*)d_in[3];
    const int* go_dst = (const int*)d_in[4];
    const int* ot_src = (const int*)d_in[5];
    const int* ot_dst = (const int*)d_in[6];
    const float* W1  = (const float*)d_in[8];
    const float* b1  = (const float*)d_in[9];
    const float* W2  = (const float*)d_in[10];
    const float* b2  = (const float*)d_in[11];
    const float* W3  = (const float*)d_in[12];
    const float* b3  = (const float*)d_in[13];
    const float* W4  = (const float*)d_in[14];
    const float* b4  = (const float*)d_in[15];
    const float* Wc1 = (const float*)d_in[16];
    const float* bc1 = (const float*)d_in[17];
    const float* Wc2 = (const float*)d_in[18];
    const float* bc2 = (const float*)d_in[19];
    float* out = (float*)d_out;

    const int N_GOAL = 16384, N_OBS = 65536, N_TASK = 8192;
    const int E1 = in_sizes[3], E2 = in_sizes[5];

    // workspace layout (~30.6 MB; round-1 proved >= 38 MB usable)
    char* w = (char*)d_ws;
    float* obs   = (float*)w;                    w += (size_t)N_OBS * 64 * 4;   // 16 MB
    float* xg1   = (float*)w;                    w += (size_t)N_GOAL * 64 * 4;  //  4 MB
    float* acc2  = (float*)w;                    w += (size_t)N_TASK * 64 * 4;  //  2 MB
    float* x2    = (float*)w;                    w += (size_t)N_TASK * 4;       // 32 KB
    int*   offs1 = (int*)w;                      w += (size_t)(N_OBS + 1) * 4;
    int*   cur1  = (int*)w;                      w += (size_t)N_OBS * 4;
    int*   srcs1 = (int*)w;                      w += (size_t)E1 * 4;           //  4 MB
    int*   offs2 = (int*)w;                      w += (size_t)(N_TASK + 1) * 4;
    int*   cur2  = (int*)w;                      w += (size_t)N_TASK * 4;
    int*   srcs2 = (int*)w;                      w += (size_t)E2 * 4;           //  4 MB

    // --- CSR builds (int atomics only: 2M increments vs 128M f32 atomics) ---
    hipMemsetAsync(cur1, 0, (size_t)N_OBS * 4, stream);
    hipMemsetAsync(cur2, 0, (size_t)N_TASK * 4, stream);
    hist_kernel<<<(E1 + 255) / 256, 256, 0, stream>>>(go_dst, cur1, E1);
    hist_kernel<<<(E2 + 255) / 256, 256, 0, stream>>>(ot_dst, cur2, E2);
    scan_csr<65536, 64><<<1, 1024, 0, stream>>>(cur1, offs1);
    scan_csr<8192, 8><<<1, 1024, 0, stream>>>(cur2, offs2);
    fill_kernel<<<(E1 + 255) / 256, 256, 0, stream>>>(go_src, go_dst, cur1, srcs1, E1);
    fill_kernel<<<(E2 + 255) / 256, 256, 0, stream>>>(ot_src, ot_dst, cur2, srcs2, E2);

    // --- dense + gather pipeline ---
    gemm_k128<<<N_GOAL / 16, 256, 0, stream>>>(x_goal, W1, xg1, N_GOAL);
    gemm_k128<<<N_OBS / 16, 256, 0, stream>>>(x_obs, W1, obs, N_OBS);
    gather_add64<true><<<N_OBS / 4, 256, 0, stream>>>(offs1, srcs1, xg1, obs, N_OBS);
    mlp_obs<<<N_OBS / 16, 256, 0, stream>>>(obs, b1, W2, b2, obs, N_OBS);   // in-place
    gather_add64<false><<<N_TASK / 4, 256, 0, stream>>>(offs2, srcs2, obs, acc2, N_TASK);
    mlp_task<<<N_TASK / 16, 256, 0, stream>>>(x_task, acc2, W3, b3, W4, b4, x2, N_TASK);
    pool_critic<<<1, 256, 0, stream>>>(x2, Wc1, bc1, Wc2, bc2, out);
}